// Round 1
// baseline (10674.741 us; speedup 1.0000x reference)
//
#include <hip/hip_runtime.h>
#include <hip/hip_fp16.h>

// Problem constants (match reference)
constexpr int BB  = 8;     // batch
constexpr int NN  = 4096;  // H*W
constexpr int CC  = 256;   // channels
constexpr int CKK = 32;    // key/query dim (C/8)
constexpr int TQ  = 4;     // queries per block in attention kernel
constexpr int PX  = 4;     // pixels per block in projection kernels

// ---------------------------------------------------------------------------
// K1: f = x@Wf+bf, g = x@Wg+bg, hh = x@Wh+bh   (per-pixel 1x1 convs)
// PX pixels per block to reuse each Wh column load across 4 FMAs.
// ---------------------------------------------------------------------------
__global__ __launch_bounds__(256) void fgh_kernel(
    const float* __restrict__ x,
    const float* __restrict__ Wf, const float* __restrict__ bf,
    const float* __restrict__ Wg, const float* __restrict__ bg,
    const float* __restrict__ Wh, const float* __restrict__ bh,
    float* __restrict__ f, float* __restrict__ g, float* __restrict__ hh)
{
    __shared__ float xs[PX][CC];
    const int t  = threadIdx.x;
    const int p0 = blockIdx.x * PX;

    #pragma unroll
    for (int px = 0; px < PX; ++px)
        xs[px][t] = x[(size_t)(p0 + px) * CC + t];
    __syncthreads();

    // hh: thread t owns output channel t
    float acc[PX];
    #pragma unroll
    for (int px = 0; px < PX; ++px) acc[px] = bh[t];
    for (int c = 0; c < CC; ++c) {
        const float w = Wh[(size_t)c * CC + t];   // coalesced, L2-resident
        #pragma unroll
        for (int px = 0; px < PX; ++px) acc[px] = fmaf(xs[px][c], w, acc[px]);
    }
    #pragma unroll
    for (int px = 0; px < PX; ++px)
        hh[(size_t)(p0 + px) * CC + t] = acc[px];

    // f (threads 0..31) and g (threads 32..63)
    if (t < CKK) {
        float a[PX];
        #pragma unroll
        for (int px = 0; px < PX; ++px) a[px] = bf[t];
        for (int c = 0; c < CC; ++c) {
            const float w = Wf[(size_t)c * CKK + t];
            #pragma unroll
            for (int px = 0; px < PX; ++px) a[px] = fmaf(xs[px][c], w, a[px]);
        }
        #pragma unroll
        for (int px = 0; px < PX; ++px)
            f[(size_t)(p0 + px) * CKK + t] = a[px];
    } else if (t < 2 * CKK) {
        const int tt = t - CKK;
        float a[PX];
        #pragma unroll
        for (int px = 0; px < PX; ++px) a[px] = bg[tt];
        for (int c = 0; c < CC; ++c) {
            const float w = Wg[(size_t)c * CKK + tt];
            #pragma unroll
            for (int px = 0; px < PX; ++px) a[px] = fmaf(xs[px][c], w, a[px]);
        }
        #pragma unroll
        for (int px = 0; px < PX; ++px)
            g[(size_t)(p0 + px) * CKK + tt] = a[px];
    }
}

// ---------------------------------------------------------------------------
// K2: flash-style attention. One block = TQ consecutive queries of one batch.
// Scores live in registers (TQ x 16 per thread); softmax weights stored fp16
// in LDS (32 KB); PV phase amortizes each hh load over TQ FMAs.
// b = blockIdx.x % 8 pins each batch's 4 MB hh slice to one XCD L2.
// ---------------------------------------------------------------------------
__global__ __launch_bounds__(256) void attn_kernel(
    const float* __restrict__ f, const float* __restrict__ g,
    const float* __restrict__ hh, float* __restrict__ o)
{
    __shared__ __half ps[TQ * NN];     // softmax weights, 32 KB
    __shared__ float  gq[TQ * CKK];    // the TQ query vectors
    __shared__ float  red4[4];         // cross-wave reduction scratch

    const int t   = threadIdx.x;
    const int blk = blockIdx.x;
    const int b   = blk % BB;               // batch == XCD (round-robin dispatch)
    const int i0  = (blk / BB) * TQ;        // first query of this block

    if (t < TQ * CKK) {
        const int q = t >> 5, d = t & 31;
        gq[t] = g[((size_t)(b * NN + i0 + q)) * CKK + d];
    }
    __syncthreads();

    // ---- scores: thread t handles keys j = t + k*256, k = 0..15 ----
    float sreg[TQ][NN / 256];
    const float4* f4 = (const float4*)(f + (size_t)b * NN * CKK);
    #pragma unroll
    for (int k = 0; k < NN / 256; ++k) {
        const int j = t + k * 256;
        float4 fv[CKK / 4];
        #pragma unroll
        for (int r = 0; r < CKK / 4; ++r) fv[r] = f4[(size_t)j * (CKK / 4) + r];
        #pragma unroll
        for (int q = 0; q < TQ; ++q) {
            float s = 0.f;
            #pragma unroll
            for (int r = 0; r < CKK / 4; ++r) {
                s = fmaf(fv[r].x, gq[q * CKK + 4 * r + 0], s);
                s = fmaf(fv[r].y, gq[q * CKK + 4 * r + 1], s);
                s = fmaf(fv[r].z, gq[q * CKK + 4 * r + 2], s);
                s = fmaf(fv[r].w, gq[q * CKK + 4 * r + 3], s);
            }
            sreg[q][k] = s;
        }
    }

    // ---- softmax over the 4096 keys, per query ----
    float linv[TQ];
    #pragma unroll
    for (int q = 0; q < TQ; ++q) {
        float m = -1e30f;
        #pragma unroll
        for (int k = 0; k < NN / 256; ++k) m = fmaxf(m, sreg[q][k]);
        #pragma unroll
        for (int off = 32; off; off >>= 1) m = fmaxf(m, __shfl_down(m, off));
        if ((t & 63) == 0) red4[t >> 6] = m;
        __syncthreads();
        m = fmaxf(fmaxf(red4[0], red4[1]), fmaxf(red4[2], red4[3]));
        __syncthreads();

        float lsum = 0.f;
        #pragma unroll
        for (int k = 0; k < NN / 256; ++k) {
            const float p = __expf(sreg[q][k] - m);
            ps[q * NN + t + k * 256] = __float2half(p);
            lsum += p;
        }
        #pragma unroll
        for (int off = 32; off; off >>= 1) lsum += __shfl_down(lsum, off);
        if ((t & 63) == 0) red4[t >> 6] = lsum;
        __syncthreads();
        linv[q] = 1.0f / (red4[0] + red4[1] + red4[2] + red4[3]);
        __syncthreads();
    }

    // ---- PV: thread t owns output channel t, accumulates all TQ queries ----
    float acc[TQ] = {0.f, 0.f, 0.f, 0.f};
    const float* hb = hh + (size_t)b * NN * CC + t;
    #pragma unroll 4
    for (int j = 0; j < NN; ++j) {
        const float hv = hb[(size_t)j * CC];       // coalesced across threads
        #pragma unroll
        for (int q = 0; q < TQ; ++q)
            acc[q] = fmaf(__half2float(ps[q * NN + j]), hv, acc[q]);
    }
    #pragma unroll
    for (int q = 0; q < TQ; ++q)
        o[((size_t)b * NN + i0 + q) * CC + t] = acc[q] * linv[q];
}

// ---------------------------------------------------------------------------
// K3: out = gamma * (o @ Wo + bo) + x
// ---------------------------------------------------------------------------
__global__ __launch_bounds__(256) void out_kernel(
    const float* __restrict__ o, const float* __restrict__ Wo,
    const float* __restrict__ bo, const float* __restrict__ gamma,
    const float* __restrict__ x, float* __restrict__ out)
{
    __shared__ float os[PX][CC];
    const int t  = threadIdx.x;
    const int p0 = blockIdx.x * PX;

    #pragma unroll
    for (int px = 0; px < PX; ++px)
        os[px][t] = o[(size_t)(p0 + px) * CC + t];
    __syncthreads();

    const float gm = gamma[0];
    float acc[PX];
    #pragma unroll
    for (int px = 0; px < PX; ++px) acc[px] = bo[t];
    for (int c = 0; c < CC; ++c) {
        const float w = Wo[(size_t)c * CC + t];
        #pragma unroll
        for (int px = 0; px < PX; ++px) acc[px] = fmaf(os[px][c], w, acc[px]);
    }
    #pragma unroll
    for (int px = 0; px < PX; ++px) {
        const size_t idx = (size_t)(p0 + px) * CC + t;
        out[idx] = gm * acc[px] + x[idx];
    }
}

// ---------------------------------------------------------------------------
extern "C" void kernel_launch(void* const* d_in, const int* in_sizes, int n_in,
                              void* d_out, int out_size, void* d_ws, size_t ws_size,
                              hipStream_t stream)
{
    (void)in_sizes; (void)n_in; (void)out_size; (void)ws_size;

    const float* x     = (const float*)d_in[0];
    const float* Wf    = (const float*)d_in[1];
    const float* bf    = (const float*)d_in[2];
    const float* Wg    = (const float*)d_in[3];
    const float* bg    = (const float*)d_in[4];
    const float* Wh    = (const float*)d_in[5];
    const float* bh    = (const float*)d_in[6];
    const float* Wo    = (const float*)d_in[7];
    const float* bo    = (const float*)d_in[8];
    const float* gamma = (const float*)d_in[9];
    float* out = (float*)d_out;

    // Workspace layout (floats): f | g | hh | o  = 4+4+32+32 = 72 MB
    float* ws = (float*)d_ws;
    float* f  = ws;
    float* g  = f  + (size_t)BB * NN * CKK;
    float* hh = g  + (size_t)BB * NN * CKK;
    float* o  = hh + (size_t)BB * NN * CC;

    fgh_kernel<<<BB * NN / PX, 256, 0, stream>>>(x, Wf, bf, Wg, bg, Wh, bh, f, g, hh);
    attn_kernel<<<BB * NN / TQ, 256, 0, stream>>>(f, g, hh, o);
    out_kernel<<<BB * NN / PX, 256, 0, stream>>>(o, Wo, bo, gamma, x, out);
}

// Round 2
// 597.485 us; speedup vs baseline: 17.8661x; 17.8661x over previous
//
#include <hip/hip_runtime.h>
#include <hip/hip_fp16.h>
#include <hip/hip_bf16.h>

constexpr int BB  = 8;
constexpr int NN  = 4096;
constexpr int CC  = 256;
constexpr int CKK = 32;
constexpr int PX  = 8;     // pixels per block in projection kernels

typedef __attribute__((ext_vector_type(8))) short    short8;   // 8 x bf16
typedef __attribute__((ext_vector_type(8))) _Float16 half8;    // 8 x fp16
typedef __attribute__((ext_vector_type(4))) float    f32x4;    // MFMA acc

// ---------------------------------------------------------------------------
// K1: projections. f,g in fp32 math -> bf16 hi/lo split (for 3-term S MFMA);
// hh in fp32 math -> fp16, stored TRANSPOSED hhT[b][c][n] for PV B-fragments.
// ---------------------------------------------------------------------------
__global__ __launch_bounds__(256) void fgh_kernel(
    const float* __restrict__ x,
    const float* __restrict__ Wf, const float* __restrict__ bf,
    const float* __restrict__ Wg, const float* __restrict__ bg,
    const float* __restrict__ Wh, const float* __restrict__ bh,
    __hip_bfloat16* __restrict__ fhi, __hip_bfloat16* __restrict__ flo,
    __hip_bfloat16* __restrict__ ghi, __hip_bfloat16* __restrict__ glo,
    __half* __restrict__ hhT)
{
    __shared__ float xs[PX][CC];
    const int t  = threadIdx.x;
    const int n0 = blockIdx.x * PX;        // global pixel base (b*NN + n)
    const int b  = n0 >> 12;
    const int nb = n0 & (NN - 1);

    #pragma unroll
    for (int px = 0; px < PX; ++px)
        xs[px][t] = x[(size_t)(n0 + px) * CC + t];
    __syncthreads();

    // hh: thread t owns channel t
    float acc[PX];
    #pragma unroll
    for (int px = 0; px < PX; ++px) acc[px] = bh[t];
    #pragma unroll 4
    for (int c = 0; c < CC; ++c) {
        const float w = Wh[c * CC + t];
        #pragma unroll
        for (int px = 0; px < PX; ++px) acc[px] = fmaf(xs[px][c], w, acc[px]);
    }
    __align__(16) __half hv[PX];
    #pragma unroll
    for (int px = 0; px < PX; ++px) hv[px] = __float2half(acc[px]);
    // transposed write: 16B contiguous per thread at row t
    *(float4*)&hhT[((size_t)(b * CC + t)) * NN + nb] = *(const float4*)hv;

    // f (threads 0..31), g (threads 32..63), fp32 math, bf16 hi/lo out
    if (t < 2 * CKK) {
        const float* W  = (t < CKK) ? Wf : Wg;
        const float* bi = (t < CKK) ? bf : bg;
        __hip_bfloat16* hi = (t < CKK) ? fhi : ghi;
        __hip_bfloat16* lo = (t < CKK) ? flo : glo;
        const int d = t & (CKK - 1);
        float a[PX];
        #pragma unroll
        for (int px = 0; px < PX; ++px) a[px] = bi[d];
        #pragma unroll 4
        for (int c = 0; c < CC; ++c) {
            const float w = W[c * CKK + d];
            #pragma unroll
            for (int px = 0; px < PX; ++px) a[px] = fmaf(xs[px][c], w, a[px]);
        }
        #pragma unroll
        for (int px = 0; px < PX; ++px) {
            const float v = a[px];
            const __hip_bfloat16 h = __float2bfloat16(v);
            const __hip_bfloat16 l = __float2bfloat16(v - __bfloat162float(h));
            hi[(size_t)(n0 + px) * CKK + d] = h;
            lo[(size_t)(n0 + px) * CKK + d] = l;
        }
    }
}

// ---------------------------------------------------------------------------
// K2: MFMA flash attention.
// Block = 64 queries of batch b (grid 512 = 8 XCD-pinned batches x 64 qblocks).
// 4 waves, 2x2 split: wave(qi,ci) owns 32 queries x 128 channels.
// Pass1: rowmax via hi-only bf16 S-MFMA. Pass2: 3-term bf16 S, exp->fp16 P,
// LDS roundtrip (C-layout -> A-layout, wave-private buffer, NO barriers),
// PV + rowsum via f16 MFMA with Hh B-frags straight from global hhT.
// ---------------------------------------------------------------------------
__global__ __launch_bounds__(256) void attn_kernel(
    const __hip_bfloat16* __restrict__ fhi, const __hip_bfloat16* __restrict__ flo,
    const __hip_bfloat16* __restrict__ ghi, const __hip_bfloat16* __restrict__ glo,
    const __half* __restrict__ hhT, float* __restrict__ o)
{
    // per-wave P buffer: 32 rows x 72 halfs (pad 64->72: 2-way-free banks)
    __shared__ __align__(16) unsigned short Pbuf[4][32 * 72];

    const int tid  = threadIdx.x;
    const int w    = tid >> 6;
    const int lane = tid & 63;
    const int ln   = lane & 15;      // MFMA "n/m" lane index
    const int lq   = lane >> 4;      // quad index
    const int b    = blockIdx.x & 7; // batch == XCD
    const int qb   = blockIdx.x >> 3;
    const int q0w  = qb * 64 + (w & 1) * 32;   // this wave's first query
    const int c0w  = (w >> 1) * 128;           // this wave's first channel

    const f32x4 zero = {0.f, 0.f, 0.f, 0.f};

    // G A-fragments (kept all kernel): A[m=ln][k=lq*8+j]
    short8 Ahi[2], Alo[2];
    #pragma unroll
    for (int qt = 0; qt < 2; ++qt) {
        const size_t base = ((size_t)(b * NN + q0w + qt * 16 + ln)) * CKK + lq * 8;
        Ahi[qt] = *(const short8*)&ghi[base];
        Alo[qt] = *(const short8*)&glo[base];
    }

    // ---- pass 1: row maxima (hi-only scores; error vs pass2 < ~0.1, safe) ----
    float mx[2][4];
    #pragma unroll
    for (int qt = 0; qt < 2; ++qt)
        #pragma unroll
        for (int r = 0; r < 4; ++r) mx[qt][r] = -1e30f;

    #pragma unroll 1
    for (int j0 = 0; j0 < NN; j0 += 64) {
        short8 Bf[4];
        #pragma unroll
        for (int kt = 0; kt < 4; ++kt)
            Bf[kt] = *(const short8*)&fhi[((size_t)(b * NN + j0 + kt * 16 + ln)) * CKK + lq * 8];
        #pragma unroll
        for (int qt = 0; qt < 2; ++qt)
            #pragma unroll
            for (int kt = 0; kt < 4; ++kt) {
                f32x4 s = __builtin_amdgcn_mfma_f32_16x16x32_bf16(Ahi[qt], Bf[kt], zero, 0, 0, 0);
                #pragma unroll
                for (int r = 0; r < 4; ++r) mx[qt][r] = fmaxf(mx[qt][r], s[r]);
            }
    }
    #pragma unroll
    for (int d = 1; d < 16; d <<= 1)
        #pragma unroll
        for (int qt = 0; qt < 2; ++qt)
            #pragma unroll
            for (int r = 0; r < 4; ++r)
                mx[qt][r] = fmaxf(mx[qt][r], __shfl_xor(mx[qt][r], d));

    // ---- pass 2: S (3-term), exp -> fp16 P, PV + rowsum ----
    f32x4 O[2][8], rs[2];
    #pragma unroll
    for (int qt = 0; qt < 2; ++qt) {
        rs[qt] = zero;
        #pragma unroll
        for (int ct = 0; ct < 8; ++ct) O[qt][ct] = zero;
    }
    half8 ones;
    #pragma unroll
    for (int j = 0; j < 8; ++j) ones[j] = (_Float16)1.0f;

    const int odd = lane & 1;

    #pragma unroll 1
    for (int j0 = 0; j0 < NN; j0 += 64) {
        short8 Bh[4], Bl[4];
        #pragma unroll
        for (int kt = 0; kt < 4; ++kt) {
            const size_t base = ((size_t)(b * NN + j0 + kt * 16 + ln)) * CKK + lq * 8;
            Bh[kt] = *(const short8*)&fhi[base];
            Bl[kt] = *(const short8*)&flo[base];
        }

        #pragma unroll
        for (int qt = 0; qt < 2; ++qt)
            #pragma unroll
            for (int kt = 0; kt < 4; ++kt) {
                f32x4 s = __builtin_amdgcn_mfma_f32_16x16x32_bf16(Ahi[qt], Bh[kt], zero, 0, 0, 0);
                s = __builtin_amdgcn_mfma_f32_16x16x32_bf16(Ahi[qt], Bl[kt], s, 0, 0, 0);
                s = __builtin_amdgcn_mfma_f32_16x16x32_bf16(Alo[qt], Bh[kt], s, 0, 0, 0);
                float p[4];
                #pragma unroll
                for (int r = 0; r < 4; ++r) p[r] = __expf(s[r] - mx[qt][r]);
                // C-layout -> LDS, pairing adjacent cols via shfl, rows r / r+1
                // split over even/odd lanes: one 4B write per 2 acc regs.
                #pragma unroll
                for (int pr = 0; pr < 2; ++pr) {
                    const float a0 = p[2 * pr], a1 = p[2 * pr + 1];
                    const float n0_ = __shfl_xor(a0, 1);
                    const float n1_ = __shfl_xor(a1, 1);
                    const float vlo = odd ? n1_ : a0;   // even col of the pair
                    const float vhi = odd ? a1  : n0_;  // odd col of the pair
                    const int row = qt * 16 + lq * 4 + 2 * pr + odd;
                    const int col = kt * 16 + (ln & ~1);
                    __half2 pk;
                    pk.x = __float2half(vlo);
                    pk.y = __float2half(vhi);
                    *(__half2*)&Pbuf[w][row * 72 + col] = pk;
                }
            }

        __asm__ volatile("s_waitcnt lgkmcnt(0)" ::: "memory");

        // read P back in A-layout (own wave's data: no barrier needed)
        half8 Ap[2][2];
        #pragma unroll
        for (int qt = 0; qt < 2; ++qt)
            #pragma unroll
            for (int kh = 0; kh < 2; ++kh)
                Ap[qt][kh] = *(const half8*)&Pbuf[w][(qt * 16 + ln) * 72 + kh * 32 + lq * 8];

        // rowsum via ones B-frag
        #pragma unroll
        for (int qt = 0; qt < 2; ++qt) {
            rs[qt] = __builtin_amdgcn_mfma_f32_16x16x32_f16(Ap[qt][0], ones, rs[qt], 0, 0, 0);
            rs[qt] = __builtin_amdgcn_mfma_f32_16x16x32_f16(Ap[qt][1], ones, rs[qt], 0, 0, 0);
        }

        // PV: B-frags straight from global hhT (L2-resident, XCD-pinned)
        #pragma unroll
        for (int ct = 0; ct < 8; ++ct)
            #pragma unroll
            for (int kh = 0; kh < 2; ++kh) {
                const half8 Bv = *(const half8*)
                    &hhT[((size_t)(b * CC + c0w + ct * 16 + ln)) * NN + j0 + kh * 32 + lq * 8];
                O[0][ct] = __builtin_amdgcn_mfma_f32_16x16x32_f16(Ap[0][kh], Bv, O[0][ct], 0, 0, 0);
                O[1][ct] = __builtin_amdgcn_mfma_f32_16x16x32_f16(Ap[1][kh], Bv, O[1][ct], 0, 0, 0);
            }
    }

    // ---- epilogue: normalize and store fp32 o ----
    #pragma unroll
    for (int qt = 0; qt < 2; ++qt)
        #pragma unroll
        for (int r = 0; r < 4; ++r) {
            const float linv = 1.0f / rs[qt][r];
            const int q = q0w + qt * 16 + lq * 4 + r;
            #pragma unroll
            for (int ct = 0; ct < 8; ++ct)
                o[((size_t)(b * NN + q)) * CC + c0w + ct * 16 + ln] = O[qt][ct][r] * linv;
        }
}

// ---------------------------------------------------------------------------
// K3: out = gamma * (o @ Wo + bo) + x   (fp32 VALU)
// ---------------------------------------------------------------------------
__global__ __launch_bounds__(256) void out_kernel(
    const float* __restrict__ o, const float* __restrict__ Wo,
    const float* __restrict__ bo, const float* __restrict__ gamma,
    const float* __restrict__ x, float* __restrict__ out)
{
    __shared__ float os[PX][CC];
    const int t  = threadIdx.x;
    const int p0 = blockIdx.x * PX;

    #pragma unroll
    for (int px = 0; px < PX; ++px)
        os[px][t] = o[(size_t)(p0 + px) * CC + t];
    __syncthreads();

    const float gm = gamma[0];
    float acc[PX];
    #pragma unroll
    for (int px = 0; px < PX; ++px) acc[px] = bo[t];
    #pragma unroll 4
    for (int c = 0; c < CC; ++c) {
        const float w = Wo[c * CC + t];
        #pragma unroll
        for (int px = 0; px < PX; ++px) acc[px] = fmaf(os[px][c], w, acc[px]);
    }
    #pragma unroll
    for (int px = 0; px < PX; ++px) {
        const size_t idx = (size_t)(p0 + px) * CC + t;
        out[idx] = gm * acc[px] + x[idx];
    }
}

// ---------------------------------------------------------------------------
extern "C" void kernel_launch(void* const* d_in, const int* in_sizes, int n_in,
                              void* d_out, int out_size, void* d_ws, size_t ws_size,
                              hipStream_t stream)
{
    (void)in_sizes; (void)n_in; (void)out_size; (void)ws_size;

    const float* x     = (const float*)d_in[0];
    const float* Wf    = (const float*)d_in[1];
    const float* bf    = (const float*)d_in[2];
    const float* Wg    = (const float*)d_in[3];
    const float* bg    = (const float*)d_in[4];
    const float* Wh    = (const float*)d_in[5];
    const float* bh    = (const float*)d_in[6];
    const float* Wo    = (const float*)d_in[7];
    const float* bo    = (const float*)d_in[8];
    const float* gamma = (const float*)d_in[9];
    float* out = (float*)d_out;

    // Workspace: fhi|flo|ghi|glo (bf16, 2MB each) | hhT (fp16, 16MB) | o (fp32, 32MB)
    char* ws = (char*)d_ws;
    __hip_bfloat16* fhi = (__hip_bfloat16*)ws;
    __hip_bfloat16* flo = fhi + (size_t)BB * NN * CKK;
    __hip_bfloat16* ghi = flo + (size_t)BB * NN * CKK;
    __hip_bfloat16* glo = ghi + (size_t)BB * NN * CKK;
    __half*         hhT = (__half*)(glo + (size_t)BB * NN * CKK);
    float*          o   = (float*)(hhT + (size_t)BB * CC * NN);

    fgh_kernel<<<BB * NN / PX, 256, 0, stream>>>(x, Wf, bf, Wg, bg, Wh, bh,
                                                 fhi, flo, ghi, glo, hhT);
    attn_kernel<<<BB * NN / 64, 256, 0, stream>>>(fhi, flo, ghi, glo, hhT, o);
    out_kernel<<<BB * NN / PX, 256, 0, stream>>>(o, Wo, bo, gamma, x, out);
}